// Round 9
// baseline (821.552 us; speedup 1.0000x reference)
//
#include <hip/hip_runtime.h>
#include <hip/hip_bf16.h>

// Fused Asterisk block, round 9: single fused kernel (in-kernel fp32->bf16
// convert, no prep pass) + single-buffered 52KB LDS so TWO blocks co-reside
// per CU — inter-block overlap hides the stage phase and barrier drains.
//
// Tap geometry (verified r0-r8), tap k, staged slot r (row = i0+2r-4):
//   g=0: r=2+l, dj=2k-4 | g=1: r=k+l, dj=0 | g=2: r=k+l, dj=4-2k
//   g=3: r=4-k+l, dj=2k-4      (l = local output row, i = i0+2l)
// LDS swizzle (write and read sides, verified r2-r8):
//   octet slot = owner ^ ((col>>2)&3); short-index bit5 ^= (col>>4)&1.

typedef __attribute__((ext_vector_type(8))) __bf16 bf16x8;
typedef __attribute__((ext_vector_type(4))) float f32x4;

#define HH 128
#define WW 128
#define CIN 256
#define NCHUNK 8
#define CHUNK 32
#define COLS 136
#define TROWS 6
#define BUF_SHORTS (TROWS*COLS*CHUNK)   // 26112 shorts = 52224 B (single buffer)
#define WPG (40*64*32)                  // 81920 bf16 per branch

__device__ __forceinline__ ushort f2bf(float f) {
    union { float f; unsigned u; } v; v.f = f;
    unsigned r = v.u + 0x7FFF + ((v.u >> 16) & 1);   // RNE
    return (ushort)(r >> 16);
}

// wp[((g*40 + s)*64 + m)*32 + kk] = bf16( w_g[(m*256 + (s/5)*32 + kk)*5 + (s%5)] )
__global__ void repack_w(const float* __restrict__ w0, const float* __restrict__ w1,
                         const float* __restrict__ w2, const float* __restrict__ w3,
                         ushort* __restrict__ wp) {
    int idx = blockIdx.x * 256 + threadIdx.x;   // 0..327679
    int g   = idx / WPG;
    int rem = idx - g * WPG;
    int s   = rem >> 11;
    int r2  = rem & 2047;
    int m   = r2 >> 5;
    int kk  = r2 & 31;
    int k   = s % 5;
    int cg  = s / 5;
    const float* w = (g == 0) ? w0 : (g == 1) ? w1 : (g == 2) ? w2 : w3;
    wp[idx] = f2bf(w[(m * CIN + cg * 32 + kk) * 5 + k]);
}

__global__ __launch_bounds__(512, 4)
void asterisk_mfma5(const float* __restrict__ x,
                    const ushort* __restrict__ wp,
                    const float* __restrict__ b0, const float* __restrict__ b1,
                    const float* __restrict__ b2, const float* __restrict__ b3,
                    float* __restrict__ out) {
    __shared__ __align__(16) short xs[BUF_SHORTS];

    const int t    = threadIdx.x;
    const int lane = t & 63;
    const int wid  = t >> 6;        // 0..7
    const int g    = wid & 3;       // branch
    const int l    = wid >> 2;      // local output row 0/1
    const int m16  = lane & 15;
    const int h    = lane >> 4;

    // XCD swizzle: batch = XCD (512 blocks, blocks round-robin over 8 XCDs)
    const int id = blockIdx.x;
    const int b  = id & 7;
    const int p  = id >> 3;                  // 0..63
    const int i0 = 4 * (p >> 1) + (p & 1);   // first output row of the pair
    const int i  = i0 + 2 * l;               // this wave's output row

    // ---- zero pad columns (cols 0..3, 132..135); persists across chunks ----
    for (int e = t; e < TROWS * 8 * CHUNK; e += 512) {
        int r  = e >> 8;
        int pc = (e >> 5) & 7;
        int c  = e & 31;
        int col = (pc < 4) ? pc : 128 + pc;
        xs[(r * COLS + col) * CHUNK + c] = 0;
    }
    // ---- zero out-of-bounds row planes (never re-staged) ----
    for (int r = 0; r < TROWS; ++r) {
        int row = i0 + 2 * r - 4;
        if ((unsigned)row >= HH) {
            for (int e = t; e < 128 * CHUNK; e += 512)
                xs[(r * COLS + 4) * CHUNK + e] = 0;
        }
    }

    // ---- accumulators init = bias (wave tile M=64 x N=128) ----
    const float* bias = (g == 0) ? b0 : (g == 1) ? b1 : (g == 2) ? b2 : b3;
    f32x4 acc[4][8];
#pragma unroll
    for (int mb = 0; mb < 4; ++mb) {
        f32x4 bv;
#pragma unroll
        for (int rr = 0; rr < 4; ++rr) bv[rr] = bias[mb * 16 + h * 4 + rr];
#pragma unroll
        for (int nb = 0; nb < 8; ++nb) acc[mb][nb] = bv;
    }

    // stage-thread mapping: (rh, cg, q) — rh picks 3 rows, cg a channel quad,
    // q a col quad
    const int rh = t >> 8;          // 0/1 -> rows rh*3..rh*3+2
    const int cg = (t >> 5) & 7;    // channel quad
    const int q  = t & 31;          // col quad: cols 4q..4q+3
    const float* xb = x + (size_t)b * CIN * HH * WW;
    const ushort* wg = wp + (size_t)g * WPG;
    const ushort* wl = wg + m16 * 32 + h * 8;   // A-frag base, step s: +s*2048

    bf16x8 a_cur[4], a_nxt[4];
#pragma unroll
    for (int mb = 0; mb < 4; ++mb)
        a_cur[mb] = *(const bf16x8*)(wl + mb * 512);

    for (int cc = 0; cc < NCHUNK; ++cc) {
        __syncthreads();            // previous chunk's readers done
        // ---- stage chunk cc: 32 ch x 6 rows x 128 cols, fp32 -> bf16 ----
        {
            int c0 = cc * CHUNK + cg * 4;
            int slot = cg >> 1;              // owning octet
            int sub  = (cg & 1) * 4;         // 4-short half of octet
            const float* srcc = xb + (size_t)c0 * HH * WW + q * 4;
#pragma unroll
            for (int r2 = 0; r2 < 3; ++r2) {
                int r   = rh * 3 + r2;
                int row = i0 + 2 * r - 4;
                if ((unsigned)row < HH) {
                    const float* src = srcc + (size_t)row * WW;
                    float4 v0 = *(const float4*)(src);
                    float4 v1 = *(const float4*)(src + HH * WW);
                    float4 v2 = *(const float4*)(src + 2 * HH * WW);
                    float4 v3 = *(const float4*)(src + 3 * HH * WW);
#pragma unroll
                    for (int jj = 0; jj < 4; ++jj) {
                        int col = q * 4 + 4 + jj;                 // padded col
                        int sl  = slot ^ ((col >> 2) & 3);        // octet swizzle
                        float f0 = ((const float*)&v0)[jj];
                        float f1 = ((const float*)&v1)[jj];
                        float f2 = ((const float*)&v2)[jj];
                        float f3 = ((const float*)&v3)[jj];
                        __hip_bfloat162 lo = __float22bfloat162_rn(make_float2(f0, f1));
                        __hip_bfloat162 hi = __float22bfloat162_rn(make_float2(f2, f3));
                        uint2 pk;
                        pk.x = *(unsigned*)&lo;
                        pk.y = *(unsigned*)&hi;
                        int wi = (r * COLS + col) * CHUNK + sl * 8 + sub;
                        wi ^= ((col >> 4) & 1) << 5;              // bit5 spread
                        *(uint2*)&xs[wi] = pk;
                    }
                }
            }
        }
        __syncthreads();            // stage visible
        // ---- compute: 5 taps over this chunk, A-prefetched ----
#pragma unroll
        for (int k = 0; k < 5; ++k) {
            int s = cc * 5 + k;
            if (s < 39) {            // prefetch next K-step's A (crosses chunks)
                const ushort* wk1 = wl + (size_t)(s + 1) * 2048;
#pragma unroll
                for (int mb = 0; mb < 4; ++mb)
                    a_nxt[mb] = *(const bf16x8*)(wk1 + mb * 512);
            }
            int rbase = (g == 0) ? 2 : (g == 3 ? 4 - k : k);
            int r  = rbase + l;
            int dj = (g == 1) ? 0 : (g == 2 ? 4 - 2 * k : 2 * k - 4);
            int col0 = m16 + dj + 4;
            int sl   = h ^ ((col0 >> 2) & 3);
            int base = (r * COLS + col0) * CHUNK + sl * 8;
            base ^= ((col0 >> 4) & 1) << 5;
#pragma unroll
            for (int nb = 0; nb < 8; ++nb) {
                int idx = (base + nb * 16 * CHUNK) ^ ((nb & 1) << 5);
                bf16x8 bf = *(const bf16x8*)(&xs[idx]);
#pragma unroll
                for (int mb = 0; mb < 4; ++mb)
                    acc[mb][nb] = __builtin_amdgcn_mfma_f32_16x16x32_bf16(
                        a_cur[mb], bf, acc[mb][nb], 0, 0, 0);
            }
            if (s < 39) {
#pragma unroll
                for (int mb = 0; mb < 4; ++mb) a_cur[mb] = a_nxt[mb];
            }
        }
    }

    // ---- epilogue: D[m][n], m = mb*16 + h*4 + rr (oc), n = nb*16 + m16 ----
    size_t obase = (((size_t)b * 256 + g * 64) * HH + i) * WW;
#pragma unroll
    for (int mb = 0; mb < 4; ++mb)
#pragma unroll
        for (int rr = 0; rr < 4; ++rr) {
            float* op = out + obase + (size_t)(mb * 16 + h * 4 + rr) * HH * WW + m16;
#pragma unroll
            for (int nb = 0; nb < 8; ++nb)
                op[nb * 16] = acc[mb][nb][rr];
        }
}

extern "C" void kernel_launch(void* const* d_in, const int* in_sizes, int n_in,
                              void* d_out, int out_size, void* d_ws, size_t ws_size,
                              hipStream_t stream) {
    const float* x    = (const float*)d_in[0];
    const float* w_h  = (const float*)d_in[1];
    const float* b_h  = (const float*)d_in[2];
    const float* w_v  = (const float*)d_in[3];
    const float* b_v  = (const float*)d_in[4];
    const float* w_d1 = (const float*)d_in[5];
    const float* b_d1 = (const float*)d_in[6];
    const float* w_d2 = (const float*)d_in[7];
    const float* b_d2 = (const float*)d_in[8];
    float* out = (float*)d_out;
    ushort* wpack = (ushort*)d_ws;   // needs 655,360 B

    repack_w<<<1280, 256, 0, stream>>>(w_h, w_v, w_d1, w_d2, wpack);
    asterisk_mfma5<<<512, 512, 0, stream>>>(x, wpack, b_h, b_v, b_d1, b_d2, out);
}

// Round 10
// 139.863 us; speedup vs baseline: 5.8740x; 5.8740x over previous
//
#include <hip/hip_runtime.h>
#include <hip/hip_bf16.h>

// Fused Asterisk block, round 10: r6 structure + 8-phase-style schedule.
// Per chunk: 5 tap-phases {A-prefetch + 8 ds_read -> setprio(1) -> 32 MFMA ->
// setprio(0) -> raw s_barrier}; vmcnt(0)+barrier only at chunk start (stage
// gll16s issued a full chunk earlier). Stage loads unconditional via a
// zero-plane (clean counts, no divergence). Raw barriers never drain vmcnt.
//
// Tap geometry (verified r0-r9), tap k, staged slot r (row = i0+2r-4):
//   g=0: r=2+l, dj=2k-4 | g=1: r=k+l, dj=0 | g=2: r=k+l, dj=4-2k
//   g=3: r=4-k+l, dj=2k-4      (l = local output row, i = i0+2l)
// Plane image (4096 shorts per (b,row,cc) plane), padded col pc=col+4:
//   idx = (pc*32 + ((c>>3) ^ ((pc>>2)&3))*8 + (c&7)) ^ (((pc>>4)&1)<<5) - 128

typedef __attribute__((ext_vector_type(8))) __bf16 bf16x8;
typedef __attribute__((ext_vector_type(4))) float f32x4;

#define HH 128
#define WW 128
#define CIN 256
#define NCHUNK 8
#define CHUNK 32
#define COLS 136
#define TROWS 6
#define BUF_SHORTS (TROWS*COLS*CHUNK)   // 26112 shorts; dbuf = 104448 B
#define WPG (40*64*32)                  // 81920 bf16 per branch
#define XT_OFF (1u<<20)
#define XT_BYTES (8193u*8192u)          // 8192 planes + 1 zero plane
#define PREP_BLOCKS 4096
#define REPACK_BLOCKS 160

__device__ __forceinline__ ushort f2bf(float f) {
    union { float f; unsigned u; } v; v.f = f;
    unsigned r = v.u + 0x7FFF + ((v.u >> 16) & 1);   // RNE
    return (ushort)(r >> 16);
}

__device__ __forceinline__ void gll16(const void* g, const void* l) {
    __builtin_amdgcn_global_load_lds(
        (const __attribute__((address_space(1))) unsigned*)g,
        (__attribute__((address_space(3))) unsigned*)l, 16, 0, 0);
}

// Merged prep: blocks [0,4096) convert x -> xt plane image (64B coalesced
// stores); [4096,4256) repack weights; last block zeroes the zero-plane.
__global__ void prep_all(const float* __restrict__ x,
                         const float* __restrict__ w0, const float* __restrict__ w1,
                         const float* __restrict__ w2, const float* __restrict__ w3,
                         ushort* __restrict__ wp, ushort* __restrict__ xt) {
    if (blockIdx.x < PREP_BLOCKS) {
        int t     = threadIdx.x;
        int plane = blockIdx.x * 2 + (t >> 7);   // ((b*128 + row)*8 + cc)
        int col   = t & 127;
        int cc  = plane & 7;
        int row = (plane >> 3) & 127;
        int b   = plane >> 10;
        const float* xb = x + ((size_t)b * CIN + cc * CHUNK) * (HH * WW)
                            + (size_t)row * WW + col;
        int pc = col + 4;
        int s3 = (pc >> 2) & 3;
        uint4 vo[4];
#pragma unroll
        for (int o = 0; o < 4; ++o) {
            int ch = (o ^ s3) * 8;               // source channel octet
            float f[8];
#pragma unroll
            for (int j = 0; j < 8; ++j)
                f[j] = xb[(size_t)(ch + j) * (HH*WW)];
            __hip_bfloat162 p0 = __float22bfloat162_rn(make_float2(f[0], f[1]));
            __hip_bfloat162 p1 = __float22bfloat162_rn(make_float2(f[2], f[3]));
            __hip_bfloat162 p2 = __float22bfloat162_rn(make_float2(f[4], f[5]));
            __hip_bfloat162 p3 = __float22bfloat162_rn(make_float2(f[6], f[7]));
            vo[o].x = *(unsigned*)&p0;
            vo[o].y = *(unsigned*)&p1;
            vo[o].z = *(unsigned*)&p2;
            vo[o].w = *(unsigned*)&p3;
        }
        int pcx = pc ^ ((pc >> 4) & 1);          // bit5 pair-swap, whole block
        ushort* P = xt + (size_t)plane * 4096 + (pcx * 32 - 128);
        uint4* P4 = (uint4*)P;
        P4[0] = vo[0]; P4[1] = vo[1]; P4[2] = vo[2]; P4[3] = vo[3];
    } else if (blockIdx.x < PREP_BLOCKS + REPACK_BLOCKS) {
        int tid2 = (blockIdx.x - PREP_BLOCKS) * 256 + threadIdx.x;  // 0..40959
#pragma unroll
        for (int e = 0; e < 8; ++e) {
            int idx = tid2 + e * (REPACK_BLOCKS * 256);   // 0..327679
            int g   = idx / WPG;
            int rem = idx - g * WPG;
            int s   = rem >> 11;
            int r2  = rem & 2047;
            int m   = r2 >> 5;
            int kk  = r2 & 31;
            int k   = s % 5;
            int cg  = s / 5;
            const float* w = (g == 0) ? w0 : (g == 1) ? w1 : (g == 2) ? w2 : w3;
            wp[idx] = f2bf(w[(m * CIN + cg * 32 + kk) * 5 + k]);
        }
    } else {
        uint4 z = {0, 0, 0, 0};
        uint4* Z = (uint4*)(xt + (size_t)8192 * 4096);
        Z[threadIdx.x * 2]     = z;
        Z[threadIdx.x * 2 + 1] = z;
    }
}

__global__ __launch_bounds__(512, 2)
void asterisk_mfma6(const ushort* __restrict__ xt,
                    const ushort* __restrict__ wp,
                    const float* __restrict__ b0, const float* __restrict__ b1,
                    const float* __restrict__ b2, const float* __restrict__ b3,
                    float* __restrict__ out) {
    __shared__ __align__(16) short xs[2][BUF_SHORTS];

    const int t    = threadIdx.x;
    const int lane = t & 63;
    const int wid  = t >> 6;        // 0..7
    const int g    = wid & 3;       // branch
    const int l    = wid >> 2;      // local output row 0/1
    const int m16  = lane & 15;
    const int h    = lane >> 4;

    // one batch per XCD (512 blocks round-robin over 8 XCDs)
    const int id = blockIdx.x;
    const int b  = id & 7;
    const int p  = id >> 3;                  // 0..63
    const int i0 = 4 * (p >> 1) + (p & 1);   // block covers rows {i0, i0+2}
    const int i  = i0 + 2 * l;               // this wave's output row

    const ushort* zp = xt + (size_t)8192 * 4096;   // zero plane

    // ---- zero pad columns (both buffers); published at first chunk barrier ----
    for (int e = t; e < 2 * TROWS * 8 * CHUNK; e += 512) {
        int s    = e;
        int bufi = s >= TROWS * 8 * CHUNK;
        if (bufi) s -= TROWS * 8 * CHUNK;
        int r  = s >> 8;
        int pc = (s >> 5) & 7;
        int c  = s & 31;
        int col = (pc < 4) ? pc : 128 + pc;
        xs[bufi][(r * COLS + col) * CHUNK + c] = 0;
    }

    // ---- accumulators init = bias (wave tile M=64 x N=128) ----
    const float* bias = (g == 0) ? b0 : (g == 1) ? b1 : (g == 2) ? b2 : b3;
    f32x4 acc[4][8];
#pragma unroll
    for (int mb = 0; mb < 4; ++mb) {
        f32x4 bv;
#pragma unroll
        for (int rr = 0; rr < 4; ++rr) bv[rr] = bias[mb * 16 + h * 4 + rr];
#pragma unroll
        for (int nb = 0; nb < 8; ++nb) acc[mb][nb] = bv;
    }

    const ushort* wg = wp + (size_t)g * WPG;
    const size_t pbase = (size_t)b * 128 * 8;

    // ---- STAGE: 6 planes -> buffer sel; UNCONDITIONAL (zero-plane for OOB) ----
    auto stage = [&](int cc, int sel) {
#pragma unroll
        for (int r = 0; r < TROWS; ++r) {
            int row = i0 + 2 * r - 4;
            const ushort* plane = ((unsigned)row < HH)
                ? xt + (pbase + (size_t)row * 8 + cc) * 4096 : zp;
            gll16(plane + wid * 512 + lane * 8,
                  &xs[sel][r * (COLS * CHUNK) + 128 + wid * 512]);
        }
    };

    stage(0, 0);

    const ushort* wl = wg + m16 * 32 + h * 8;   // A-frag base; K-step s: +s*2048
    bf16x8 a_cur[4], a_nxt[4];
#pragma unroll
    for (int mb = 0; mb < 4; ++mb)
        a_cur[mb] = *(const bf16x8*)(wl + mb * 512);

    for (int cc = 0; cc < NCHUNK; ++cc) {
        const int sel = cc & 1;
        const short* xsel = xs[sel];
#pragma unroll
        for (int k = 0; k < 5; ++k) {
            int s = cc * 5 + k;
            if (k == 0) {
                // chunk handoff: own stage loads landed (issued a full chunk
                // ago) + pad zeros visible; then publish to all waves.
                asm volatile("s_waitcnt vmcnt(0) lgkmcnt(0)" ::: "memory");
                __builtin_amdgcn_s_barrier();
                if (cc < NCHUNK - 1) stage(cc + 1, sel ^ 1);
            }
            if (s < 39) {            // A-prefetch stays in flight across barriers
                const ushort* wk1 = wl + (size_t)(s + 1) * 2048;
#pragma unroll
                for (int mb = 0; mb < 4; ++mb)
                    a_nxt[mb] = *(const bf16x8*)(wk1 + mb * 512);
            }
            int rbase = (g == 0) ? 2 : (g == 3 ? 4 - k : k);
            int r  = rbase + l;
            int dj = (g == 1) ? 0 : (g == 2 ? 4 - 2 * k : 2 * k - 4);
            int col0 = m16 + dj + 4;
            int sl   = h ^ ((col0 >> 2) & 3);
            int base = (r * COLS + col0) * CHUNK + sl * 8;
            base ^= ((col0 >> 4) & 1) << 5;

            bf16x8 bf[8];
#pragma unroll
            for (int nb = 0; nb < 8; ++nb) {
                int idx = (base + nb * 16 * CHUNK) ^ ((nb & 1) << 5);
                bf[nb] = *(const bf16x8*)(&xsel[idx]);
            }
            __builtin_amdgcn_s_setprio(1);
#pragma unroll
            for (int nb = 0; nb < 8; ++nb)
#pragma unroll
                for (int mb = 0; mb < 4; ++mb)
                    acc[mb][nb] = __builtin_amdgcn_mfma_f32_16x16x32_bf16(
                        a_cur[mb], bf[nb], acc[mb][nb], 0, 0, 0);
            __builtin_amdgcn_s_setprio(0);
            if (s < 39) {
#pragma unroll
                for (int mb = 0; mb < 4; ++mb) a_cur[mb] = a_nxt[mb];
            }
            if (k < 4) __builtin_amdgcn_s_barrier();   // phase gate (no drain)
        }
    }

    // ---- epilogue: D[m][n], m = mb*16 + h*4 + rr (oc), n = nb*16 + m16 ----
    size_t obase = (((size_t)b * 256 + g * 64) * HH + i) * WW;
#pragma unroll
    for (int mb = 0; mb < 4; ++mb)
#pragma unroll
        for (int rr = 0; rr < 4; ++rr) {
            float* op = out + obase + (size_t)(mb * 16 + h * 4 + rr) * HH * WW + m16;
#pragma unroll
            for (int nb = 0; nb < 8; ++nb)
                op[nb * 16] = acc[mb][nb][rr];
        }
}

// ---------------- fallback (round-3 kernel) if ws too small ----------------
#define XS_ELEMS (5*COLS*CHUNK)
__global__ void repack_w_fb(const float* __restrict__ w0, const float* __restrict__ w1,
                            const float* __restrict__ w2, const float* __restrict__ w3,
                            ushort* __restrict__ wp) {
    int idx = blockIdx.x * 256 + threadIdx.x;
    int g   = idx / WPG;
    int rem = idx - g * WPG;
    int s   = rem >> 11;
    int r2  = rem & 2047;
    int m   = r2 >> 5;
    int kk  = r2 & 31;
    int k   = s % 5;
    int cg  = s / 5;
    const float* w = (g == 0) ? w0 : (g == 1) ? w1 : (g == 2) ? w2 : w3;
    wp[idx] = f2bf(w[(m * CIN + cg * 32 + kk) * 5 + k]);
}

__global__ __launch_bounds__(256, 4)
void asterisk_mfma_fb(const float* __restrict__ x,
                      const ushort* __restrict__ wp,
                      const float* __restrict__ b0, const float* __restrict__ b1,
                      const float* __restrict__ b2, const float* __restrict__ b3,
                      float* __restrict__ out) {
    __shared__ __align__(16) short xs[XS_ELEMS];
    const int t    = threadIdx.x;
    const int lane = t & 63;
    const int wid  = t >> 6;
    const int m16  = lane & 15;
    const int h    = lane >> 4;
    int id = blockIdx.x;
    int sw = (id & 7) * 128 + (id >> 3);
    const int b = sw >> 7;
    const int i = sw & 127;
    for (int e = t; e < 5 * 8 * CHUNK; e += 256) {
        int r  = e >> 8;
        int pc = (e >> 5) & 7;
        int c  = e & 31;
        int col = (pc < 4) ? pc : 128 + pc;
        xs[(r * COLS + col) * CHUNK + c] = 0;
    }
    for (int r = 0; r < 5; ++r) {
        int row = i + 2 * r - 4;
        if ((unsigned)row >= HH)
            for (int e = t; e < COLS * CHUNK; e += 256)
                xs[r * COLS * CHUNK + e] = 0;
    }
    const float* bias = (wid == 0) ? b0 : (wid == 1) ? b1 : (wid == 2) ? b2 : b3;
    f32x4 acc[4][8];
#pragma unroll
    for (int mb = 0; mb < 4; ++mb) {
        f32x4 bv;
#pragma unroll
        for (int rr = 0; rr < 4; ++rr) bv[rr] = bias[mb * 16 + h * 4 + rr];
#pragma unroll
        for (int nb = 0; nb < 8; ++nb) acc[mb][nb] = bv;
    }
    const int cg = t >> 5;
    const int q  = t & 31;
    const float* xb = x + (size_t)b * CIN * HH * WW;
    const ushort* wg = wp + (size_t)wid * WPG;
    for (int cc = 0; cc < NCHUNK; ++cc) {
        __syncthreads();
        {
            int c0 = cc * CHUNK + cg * 4;
            int slot = cg >> 1;
            int sub  = (cg & 1) * 4;
            const float* srcc = xb + (size_t)c0 * HH * WW + q * 4;
#pragma unroll
            for (int r = 0; r < 5; ++r) {
                int row = i + 2 * r - 4;
                if ((unsigned)row < HH) {
                    const float* src = srcc + (size_t)row * WW;
                    float4 v0 = *(const float4*)(src);
                    float4 v1 = *(const float4*)(src + HH * WW);
                    float4 v2 = *(const float4*)(src + 2 * HH * WW);
                    float4 v3 = *(const float4*)(src + 3 * HH * WW);
#pragma unroll
                    for (int jj = 0; jj < 4; ++jj) {
                        int col = q * 4 + 4 + jj;
                        int sl  = slot ^ ((col >> 2) & 3);
                        float f0 = ((const float*)&v0)[jj];
                        float f1 = ((const float*)&v1)[jj];
                        float f2 = ((const float*)&v2)[jj];
                        float f3 = ((const float*)&v3)[jj];
                        __hip_bfloat162 lo = __float22bfloat162_rn(make_float2(f0, f1));
                        __hip_bfloat162 hi = __float22bfloat162_rn(make_float2(f2, f3));
                        uint2 pk;
                        pk.x = *(unsigned*)&lo;
                        pk.y = *(unsigned*)&hi;
                        int wi = (r * COLS + col) * CHUNK + sl * 8 + sub;
                        wi ^= ((col >> 4) & 1) << 5;
                        *(uint2*)&xs[wi] = pk;
                    }
                }
            }
        }
        __syncthreads();
        const ushort* wc = wg + (size_t)(cc * 5 * 64 * 32) + m16 * 32 + h * 8;
        bf16x8 a_cur[4], a_nxt[4];
#pragma unroll
        for (int mb = 0; mb < 4; ++mb)
            a_cur[mb] = *(const bf16x8*)(wc + mb * 16 * 32);
#pragma unroll
        for (int k = 0; k < 5; ++k) {
            if (k < 4) {
                const ushort* wk1 = wc + (size_t)(k + 1) * 64 * 32;
#pragma unroll
                for (int mb = 0; mb < 4; ++mb)
                    a_nxt[mb] = *(const bf16x8*)(wk1 + mb * 16 * 32);
            }
            int r  = (wid == 0) ? 2 : (wid == 3 ? 4 - k : k);
            int dj = (wid == 1) ? 0 : (wid == 2 ? 4 - 2 * k : 2 * k - 4);
            int col0 = m16 + dj + 4;
            int sl   = h ^ ((col0 >> 2) & 3);
            int base = (r * COLS + col0) * CHUNK + sl * 8;
            base ^= ((col0 >> 4) & 1) << 5;
#pragma unroll
            for (int nb = 0; nb < 8; ++nb) {
                int idx = (base + nb * 16 * CHUNK) ^ ((nb & 1) << 5);
                bf16x8 bf = *(const bf16x8*)(&xs[idx]);
#pragma unroll
                for (int mb = 0; mb < 4; ++mb)
                    acc[mb][nb] = __builtin_amdgcn_mfma_f32_16x16x32_bf16(
                        a_cur[mb], bf, acc[mb][nb], 0, 0, 0);
            }
            if (k < 4) {
#pragma unroll
                for (int mb = 0; mb < 4; ++mb) a_cur[mb] = a_nxt[mb];
            }
        }
    }
    size_t obase = (((size_t)b * 256 + wid * 64) * HH + i) * WW;
#pragma unroll
    for (int mb = 0; mb < 4; ++mb)
#pragma unroll
        for (int rr = 0; rr < 4; ++rr) {
            float* op = out + obase + (size_t)(mb * 16 + h * 4 + rr) * HH * WW + m16;
#pragma unroll
            for (int nb = 0; nb < 8; ++nb)
                op[nb * 16] = acc[mb][nb][rr];
        }
}

extern "C" void kernel_launch(void* const* d_in, const int* in_sizes, int n_in,
                              void* d_out, int out_size, void* d_ws, size_t ws_size,
                              hipStream_t stream) {
    const float* x    = (const float*)d_in[0];
    const float* w_h  = (const float*)d_in[1];
    const float* b_h  = (const float*)d_in[2];
    const float* w_v  = (const float*)d_in[3];
    const float* b_v  = (const float*)d_in[4];
    const float* w_d1 = (const float*)d_in[5];
    const float* b_d1 = (const float*)d_in[6];
    const float* w_d2 = (const float*)d_in[7];
    const float* b_d2 = (const float*)d_in[8];
    float* out = (float*)d_out;
    ushort* wpack = (ushort*)d_ws;

    if (ws_size >= (size_t)XT_OFF + (size_t)XT_BYTES) {
        ushort* xt = (ushort*)((char*)d_ws + XT_OFF);
        prep_all<<<PREP_BLOCKS + REPACK_BLOCKS + 1, 256, 0, stream>>>(
            x, w_h, w_v, w_d1, w_d2, wpack, xt);
        asterisk_mfma6<<<512, 512, 0, stream>>>(xt, wpack, b_h, b_v, b_d1, b_d2, out);
    } else {
        repack_w_fb<<<1280, 256, 0, stream>>>(w_h, w_v, w_d1, w_d2, wpack);
        asterisk_mfma_fb<<<1024, 256, 0, stream>>>(x, wpack, b_h, b_v, b_d1, b_d2, out);
    }
}

// Round 11
// 106.107 us; speedup vs baseline: 7.7426x; 1.3181x over previous
//
#include <hip/hip_runtime.h>
#include <hip/hip_bf16.h>

// Fused Asterisk block, round 11: single fused kernel (r9 structure, spill
// fixed) + T14 async-stage split. 512 thr, 2 output rows/block, 52KB
// single-buffer LDS. Per chunk: sync -> cvt+ds_write -> sync -> issue next
// chunk's global loads into regs -> 5 tap MFMA phases (loads fly under MFMA).
//
// Tap geometry (verified r0-r10), tap k, staged slot r (row = i0+2r-4):
//   g=0: r=2+l, dj=2k-4 | g=1: r=k+l, dj=0 | g=2: r=k+l, dj=4-2k
//   g=3: r=4-k+l, dj=2k-4      (l = local output row, i = i0+2l)
// LDS swizzle (write and read, verified r2-r10):
//   octet slot = owner ^ ((col>>2)&3); short-index bit5 ^= (col>>4)&1.

typedef __attribute__((ext_vector_type(8))) __bf16 bf16x8;
typedef __attribute__((ext_vector_type(4))) float f32x4;

#define HH 128
#define WW 128
#define CIN 256
#define NCHUNK 8
#define CHUNK 32
#define COLS 136
#define TROWS 6
#define BUF_SHORTS (TROWS*COLS*CHUNK)   // 26112 shorts = 52224 B (single buffer)
#define WPG (40*64*32)                  // 81920 bf16 per branch

__device__ __forceinline__ ushort f2bf(float f) {
    union { float f; unsigned u; } v; v.f = f;
    unsigned r = v.u + 0x7FFF + ((v.u >> 16) & 1);   // RNE
    return (ushort)(r >> 16);
}

// wp[((g*40 + s)*64 + m)*32 + kk] = bf16( w_g[(m*256 + (s/5)*32 + kk)*5 + (s%5)] )
__global__ void repack_w(const float* __restrict__ w0, const float* __restrict__ w1,
                         const float* __restrict__ w2, const float* __restrict__ w3,
                         ushort* __restrict__ wp) {
    int idx = blockIdx.x * 256 + threadIdx.x;   // 0..327679
    int g   = idx / WPG;
    int rem = idx - g * WPG;
    int s   = rem >> 11;
    int r2  = rem & 2047;
    int m   = r2 >> 5;
    int kk  = r2 & 31;
    int k   = s % 5;
    int cg  = s / 5;
    const float* w = (g == 0) ? w0 : (g == 1) ? w1 : (g == 2) ? w2 : w3;
    wp[idx] = f2bf(w[(m * CIN + cg * 32 + kk) * 5 + k]);
}

__global__ __launch_bounds__(512, 2)
void asterisk_mfma7(const float* __restrict__ x,
                    const ushort* __restrict__ wp,
                    const float* __restrict__ b0, const float* __restrict__ b1,
                    const float* __restrict__ b2, const float* __restrict__ b3,
                    float* __restrict__ out) {
    __shared__ __align__(16) short xs[BUF_SHORTS];

    const int t    = threadIdx.x;
    const int lane = t & 63;
    const int wid  = t >> 6;        // 0..7
    const int g    = wid & 3;       // branch
    const int l    = wid >> 2;      // local output row 0/1
    const int m16  = lane & 15;
    const int h    = lane >> 4;

    // one batch per XCD (512 blocks round-robin over 8 XCDs)
    const int id = blockIdx.x;
    const int b  = id & 7;
    const int p  = id >> 3;                  // 0..63
    const int i0 = 4 * (p >> 1) + (p & 1);   // block covers rows {i0, i0+2}
    const int i  = i0 + 2 * l;               // this wave's output row

    // ---- zero pad columns (cols 0..3, 132..135); persists (never re-staged) ----
    for (int e = t; e < TROWS * 8 * CHUNK; e += 512) {
        int r  = e >> 8;
        int pc = (e >> 5) & 7;
        int c  = e & 31;
        int col = (pc < 4) ? pc : 128 + pc;
        xs[(r * COLS + col) * CHUNK + c] = 0;
    }

    // ---- accumulators init = bias (wave tile M=64 x N=128) ----
    const float* bias = (g == 0) ? b0 : (g == 1) ? b1 : (g == 2) ? b2 : b3;
    f32x4 acc[4][8];
#pragma unroll
    for (int mb = 0; mb < 4; ++mb) {
        f32x4 bv;
#pragma unroll
        for (int rr = 0; rr < 4; ++rr) bv[rr] = bias[mb * 16 + h * 4 + rr];
#pragma unroll
        for (int nb = 0; nb < 8; ++nb) acc[mb][nb] = bv;
    }

    // ---- stage-thread mapping: (rh, cg, q) ----
    const int rh = t >> 8;          // 0/1 -> rows rh*3..rh*3+2
    const int cg = (t >> 5) & 7;    // channel quad within chunk
    const int q  = t & 31;          // col quad: cols 4q..4q+3
    const float* xb = x + (size_t)b * CIN * HH * WW;

    bool rowok[3];
    const float* rowp[3];
#pragma unroll
    for (int r2 = 0; r2 < 3; ++r2) {
        int r   = rh * 3 + r2;
        int row = i0 + 2 * r - 4;
        rowok[r2] = (unsigned)row < HH;
        rowp[r2]  = xb + (size_t)(cg * 4) * (HH * WW) + (size_t)(rowok[r2] ? row : 0) * WW + q * 4;
    }

    float4 st[3][4];   // staged fp32: [local row][channel] x 4 cols = 48 VGPRs

    auto loadchunk = [&](int cc) {
        size_t coff = (size_t)cc * CHUNK * (HH * WW);
#pragma unroll
        for (int r2 = 0; r2 < 3; ++r2) {
            if (rowok[r2]) {
                const float* src = rowp[r2] + coff;
                st[r2][0] = *(const float4*)(src);
                st[r2][1] = *(const float4*)(src + HH * WW);
                st[r2][2] = *(const float4*)(src + 2 * (HH * WW));
                st[r2][3] = *(const float4*)(src + 3 * (HH * WW));
            } else {
                float4 z = {0.f, 0.f, 0.f, 0.f};
                st[r2][0] = z; st[r2][1] = z; st[r2][2] = z; st[r2][3] = z;
            }
        }
    };

    auto writechunk = [&]() {
        int slot = cg >> 1;              // owning octet
        int sub  = (cg & 1) * 4;         // 4-short half of octet
#pragma unroll
        for (int r2 = 0; r2 < 3; ++r2) {
            int r = rh * 3 + r2;
#pragma unroll
            for (int jj = 0; jj < 4; ++jj) {
                int col = q * 4 + 4 + jj;                 // padded col
                int sl  = slot ^ ((col >> 2) & 3);        // octet swizzle
                float f0 = ((const float*)&st[r2][0])[jj];
                float f1 = ((const float*)&st[r2][1])[jj];
                float f2 = ((const float*)&st[r2][2])[jj];
                float f3 = ((const float*)&st[r2][3])[jj];
                __hip_bfloat162 lo = __float22bfloat162_rn(make_float2(f0, f1));
                __hip_bfloat162 hi = __float22bfloat162_rn(make_float2(f2, f3));
                uint2 pk;
                pk.x = *(unsigned*)&lo;
                pk.y = *(unsigned*)&hi;
                int wi = (r * COLS + col) * CHUNK + sl * 8 + sub;
                wi ^= ((col >> 4) & 1) << 5;              // bit5 spread
                *(uint2*)&xs[wi] = pk;
            }
        }
    };

    const ushort* wl = wp + (size_t)g * WPG + m16 * 32 + h * 8;  // A base; +s*2048
    bf16x8 a_cur[4], a_nxt[4];
#pragma unroll
    for (int mb = 0; mb < 4; ++mb)
        a_cur[mb] = *(const bf16x8*)(wl + mb * 512);

    loadchunk(0);   // prologue loads (latency exposed once)

    for (int cc = 0; cc < NCHUNK; ++cc) {
        __syncthreads();            // all waves finished reading previous chunk
        writechunk();               // cvt + ds_write (vmcnt wait on st is stale)
        __syncthreads();            // writes visible; nothing young in flight
        if (cc < NCHUNK - 1) loadchunk(cc + 1);   // fire-and-forget under MFMA

        // ---- compute: 5 taps over this chunk ----
#pragma unroll
        for (int k = 0; k < 5; ++k) {
            int s = cc * 5 + k;
            if (s < 39) {            // A-prefetch (L2-resident weights)
                const ushort* wk1 = wl + (size_t)(s + 1) * 2048;
#pragma unroll
                for (int mb = 0; mb < 4; ++mb)
                    a_nxt[mb] = *(const bf16x8*)(wk1 + mb * 512);
            }
            int rbase = (g == 0) ? 2 : (g == 3 ? 4 - k : k);
            int r  = rbase + l;
            int dj = (g == 1) ? 0 : (g == 2 ? 4 - 2 * k : 2 * k - 4);
            int col0 = m16 + dj + 4;
            int sl   = h ^ ((col0 >> 2) & 3);
            int base = (r * COLS + col0) * CHUNK + sl * 8;
            base ^= ((col0 >> 4) & 1) << 5;

            __builtin_amdgcn_s_setprio(1);
#pragma unroll
            for (int nb = 0; nb < 8; ++nb) {
                int idx = (base + nb * 16 * CHUNK) ^ ((nb & 1) << 5);
                bf16x8 bf = *(const bf16x8*)(&xs[idx]);
#pragma unroll
                for (int mb = 0; mb < 4; ++mb)
                    acc[mb][nb] = __builtin_amdgcn_mfma_f32_16x16x32_bf16(
                        a_cur[mb], bf, acc[mb][nb], 0, 0, 0);
            }
            __builtin_amdgcn_s_setprio(0);
            if (s < 39) {
#pragma unroll
                for (int mb = 0; mb < 4; ++mb) a_cur[mb] = a_nxt[mb];
            }
        }
    }

    // ---- epilogue: D[m][n], m = mb*16 + h*4 + rr (oc), n = nb*16 + m16 ----
    size_t obase = (((size_t)b * 256 + g * 64) * HH + i) * WW;
#pragma unroll
    for (int mb = 0; mb < 4; ++mb)
#pragma unroll
        for (int rr = 0; rr < 4; ++rr) {
            float* op = out + obase + (size_t)(mb * 16 + h * 4 + rr) * HH * WW + m16;
#pragma unroll
            for (int nb = 0; nb < 8; ++nb)
                op[nb * 16] = acc[mb][nb][rr];
        }
}

extern "C" void kernel_launch(void* const* d_in, const int* in_sizes, int n_in,
                              void* d_out, int out_size, void* d_ws, size_t ws_size,
                              hipStream_t stream) {
    const float* x    = (const float*)d_in[0];
    const float* w_h  = (const float*)d_in[1];
    const float* b_h  = (const float*)d_in[2];
    const float* w_v  = (const float*)d_in[3];
    const float* b_v  = (const float*)d_in[4];
    const float* w_d1 = (const float*)d_in[5];
    const float* b_d1 = (const float*)d_in[6];
    const float* w_d2 = (const float*)d_in[7];
    const float* b_d2 = (const float*)d_in[8];
    float* out = (float*)d_out;
    ushort* wpack = (ushort*)d_ws;   // needs 655,360 B

    repack_w<<<1280, 256, 0, stream>>>(w_h, w_v, w_d1, w_d2, wpack);
    asterisk_mfma7<<<512, 512, 0, stream>>>(x, wpack, b_h, b_v, b_d1, b_d2, out);
}

// Round 12
// 100.896 us; speedup vs baseline: 8.1426x; 1.0517x over previous
//
#include <hip/hip_runtime.h>
#include <hip/hip_bf16.h>

// Fused Asterisk block, round 12: r11 structure + register diet + explicit
// bf double-buffer + single-barrier-per-chunk LDS double buffer.
//   - no A-prefetch (a loaded per tap; L2-hot) -> frees 64 VGPR
//   - 2-deep bf pipeline: read bf[nb+1] during MFMA of bf[nb]
//   - dbuf LDS: {MFMA buf[sel] -> writechunk buf[sel^1] -> load cc+2 -> barrier}
//
// Tap geometry (verified r0-r11), tap k, staged slot r (row = i0+2r-4):
//   g=0: r=2+l, dj=2k-4 | g=1: r=k+l, dj=0 | g=2: r=k+l, dj=4-2k
//   g=3: r=4-k+l, dj=2k-4      (l = local output row, i = i0+2l)
// LDS swizzle (write and read, verified r2-r11):
//   octet slot = owner ^ ((col>>2)&3); short-index bit5 ^= (col>>4)&1.

typedef __attribute__((ext_vector_type(8))) __bf16 bf16x8;
typedef __attribute__((ext_vector_type(4))) float f32x4;

#define HH 128
#define WW 128
#define CIN 256
#define NCHUNK 8
#define CHUNK 32
#define COLS 136
#define TROWS 6
#define BUF_SHORTS (TROWS*COLS*CHUNK)   // 26112 shorts; dbuf = 104448 B
#define WPG (40*64*32)                  // 81920 bf16 per branch

__device__ __forceinline__ ushort f2bf(float f) {
    union { float f; unsigned u; } v; v.f = f;
    unsigned r = v.u + 0x7FFF + ((v.u >> 16) & 1);   // RNE
    return (ushort)(r >> 16);
}

// wp[((g*40 + s)*64 + m)*32 + kk] = bf16( w_g[(m*256 + (s/5)*32 + kk)*5 + (s%5)] )
__global__ void repack_w(const float* __restrict__ w0, const float* __restrict__ w1,
                         const float* __restrict__ w2, const float* __restrict__ w3,
                         ushort* __restrict__ wp) {
    int idx = blockIdx.x * 256 + threadIdx.x;   // 0..327679
    int g   = idx / WPG;
    int rem = idx - g * WPG;
    int s   = rem >> 11;
    int r2  = rem & 2047;
    int m   = r2 >> 5;
    int kk  = r2 & 31;
    int k   = s % 5;
    int cg  = s / 5;
    const float* w = (g == 0) ? w0 : (g == 1) ? w1 : (g == 2) ? w2 : w3;
    wp[idx] = f2bf(w[(m * CIN + cg * 32 + kk) * 5 + k]);
}

__global__ __launch_bounds__(512, 2)
void asterisk_mfma8(const float* __restrict__ x,
                    const ushort* __restrict__ wp,
                    const float* __restrict__ b0, const float* __restrict__ b1,
                    const float* __restrict__ b2, const float* __restrict__ b3,
                    float* __restrict__ out) {
    __shared__ __align__(16) short xs[2][BUF_SHORTS];

    const int t    = threadIdx.x;
    const int lane = t & 63;
    const int wid  = t >> 6;        // 0..7
    const int g    = wid & 3;       // branch
    const int l    = wid >> 2;      // local output row 0/1
    const int m16  = lane & 15;
    const int h    = lane >> 4;

    // one batch per XCD (512 blocks round-robin over 8 XCDs)
    const int id = blockIdx.x;
    const int b  = id & 7;
    const int p  = id >> 3;                  // 0..63
    const int i0 = 4 * (p >> 1) + (p & 1);   // block covers rows {i0, i0+2}
    const int i  = i0 + 2 * l;               // this wave's output row

    // ---- zero pad columns in BOTH buffers (cols 0..3, 132..135); persists ----
    for (int e = t; e < 2 * TROWS * 8 * CHUNK; e += 512) {
        int s    = e;
        int bufi = s >= TROWS * 8 * CHUNK;
        if (bufi) s -= TROWS * 8 * CHUNK;
        int r  = s >> 8;
        int pc = (s >> 5) & 7;
        int c  = s & 31;
        int col = (pc < 4) ? pc : 128 + pc;
        xs[bufi][(r * COLS + col) * CHUNK + c] = 0;
    }

    // ---- accumulators init = bias (wave tile M=64 x N=128) ----
    const float* bias = (g == 0) ? b0 : (g == 1) ? b1 : (g == 2) ? b2 : b3;
    f32x4 acc[4][8];
#pragma unroll
    for (int mb = 0; mb < 4; ++mb) {
        f32x4 bv;
#pragma unroll
        for (int rr = 0; rr < 4; ++rr) bv[rr] = bias[mb * 16 + h * 4 + rr];
#pragma unroll
        for (int nb = 0; nb < 8; ++nb) acc[mb][nb] = bv;
    }

    // ---- stage-thread mapping: (rh, cg, q) ----
    const int rh = t >> 8;          // 0/1 -> rows rh*3..rh*3+2
    const int cg = (t >> 5) & 7;    // channel quad within chunk
    const int q  = t & 31;          // col quad: cols 4q..4q+3
    const float* xb = x + (size_t)b * CIN * HH * WW;

    bool rowok[3];
    const float* rowp[3];
#pragma unroll
    for (int r2 = 0; r2 < 3; ++r2) {
        int r   = rh * 3 + r2;
        int row = i0 + 2 * r - 4;
        rowok[r2] = (unsigned)row < HH;
        rowp[r2]  = xb + (size_t)(cg * 4) * (HH * WW)
                       + (size_t)(rowok[r2] ? row : 0) * WW + q * 4;
    }

    float4 st[3][4];   // staged fp32: [local row][channel] x 4 cols = 48 VGPRs

    auto loadchunk = [&](int cc) {
        size_t coff = (size_t)cc * CHUNK * (HH * WW);
#pragma unroll
        for (int r2 = 0; r2 < 3; ++r2) {
            if (rowok[r2]) {
                const float* src = rowp[r2] + coff;
                st[r2][0] = *(const float4*)(src);
                st[r2][1] = *(const float4*)(src + HH * WW);
                st[r2][2] = *(const float4*)(src + 2 * (HH * WW));
                st[r2][3] = *(const float4*)(src + 3 * (HH * WW));
            } else {
                float4 z = {0.f, 0.f, 0.f, 0.f};
                st[r2][0] = z; st[r2][1] = z; st[r2][2] = z; st[r2][3] = z;
            }
        }
    };

    auto writechunk = [&](int sel) {
        int slot = cg >> 1;              // owning octet
        int sub  = (cg & 1) * 4;         // 4-short half of octet
#pragma unroll
        for (int r2 = 0; r2 < 3; ++r2) {
            int r = rh * 3 + r2;
#pragma unroll
            for (int jj = 0; jj < 4; ++jj) {
                int col = q * 4 + 4 + jj;                 // padded col
                int sl  = slot ^ ((col >> 2) & 3);        // octet swizzle
                float f0 = ((const float*)&st[r2][0])[jj];
                float f1 = ((const float*)&st[r2][1])[jj];
                float f2 = ((const float*)&st[r2][2])[jj];
                float f3 = ((const float*)&st[r2][3])[jj];
                __hip_bfloat162 lo = __float22bfloat162_rn(make_float2(f0, f1));
                __hip_bfloat162 hi = __float22bfloat162_rn(make_float2(f2, f3));
                uint2 pk;
                pk.x = *(unsigned*)&lo;
                pk.y = *(unsigned*)&hi;
                int wi = (r * COLS + col) * CHUNK + sl * 8 + sub;
                wi ^= ((col >> 4) & 1) << 5;              // bit5 spread
                *(uint2*)&xs[sel][wi] = pk;
            }
        }
    };

    const ushort* wl = wp + (size_t)g * WPG + m16 * 32 + h * 8;  // A base; +s*2048

    // ---- prologue: chunk0 -> buf0; issue chunk1 loads ----
    loadchunk(0);
    writechunk(0);          // compiler inserts vmcnt wait on st
    __syncthreads();        // buf0 + pad zeros published
    loadchunk(1);           // flies under chunk0's MFMA phase

    for (int cc = 0; cc < NCHUNK; ++cc) {
        const int sel = cc & 1;
        const short* xsel = xs[sel];

        // ---- compute: 5 taps over this chunk ----
#pragma unroll
        for (int k = 0; k < 5; ++k) {
            const ushort* wk = wl + (size_t)(cc * 5 + k) * 2048;
            bf16x8 a[4];
#pragma unroll
            for (int mb = 0; mb < 4; ++mb)
                a[mb] = *(const bf16x8*)(wk + mb * 512);

            int rbase = (g == 0) ? 2 : (g == 3 ? 4 - k : k);
            int r  = rbase + l;
            int dj = (g == 1) ? 0 : (g == 2 ? 4 - 2 * k : 2 * k - 4);
            int col0 = m16 + dj + 4;
            int sl   = h ^ ((col0 >> 2) & 3);
            int base = (r * COLS + col0) * CHUNK + sl * 8;
            base ^= ((col0 >> 4) & 1) << 5;

            bf16x8 bfc = *(const bf16x8*)(&xsel[base]);   // nb = 0
            __builtin_amdgcn_s_setprio(1);
#pragma unroll
            for (int nb = 0; nb < 8; ++nb) {
                bf16x8 bfn;
                if (nb < 7) {   // 2-deep pipeline: next read over current MFMAs
                    int idx = (base + (nb + 1) * 16 * CHUNK) ^ (((nb + 1) & 1) << 5);
                    bfn = *(const bf16x8*)(&xsel[idx]);
                }
#pragma unroll
                for (int mb = 0; mb < 4; ++mb)
                    acc[mb][nb] = __builtin_amdgcn_mfma_f32_16x16x32_bf16(
                        a[mb], bfc, acc[mb][nb], 0, 0, 0);
                if (nb < 7) bfc = bfn;
            }
            __builtin_amdgcn_s_setprio(0);
        }

        // ---- handoff: write staged chunk cc+1, issue loads cc+2, one barrier ----
        if (cc < NCHUNK - 1) {
            writechunk(sel ^ 1);
            if (cc < NCHUNK - 2) loadchunk(cc + 2);
            __syncthreads();
        }
    }

    // ---- epilogue: D[m][n], m = mb*16 + h*4 + rr (oc), n = nb*16 + m16 ----
    size_t obase = (((size_t)b * 256 + g * 64) * HH + i) * WW;
#pragma unroll
    for (int mb = 0; mb < 4; ++mb)
#pragma unroll
        for (int rr = 0; rr < 4; ++rr) {
            float* op = out + obase + (size_t)(mb * 16 + h * 4 + rr) * HH * WW + m16;
#pragma unroll
            for (int nb = 0; nb < 8; ++nb)
                op[nb * 16] = acc[mb][nb][rr];
        }
}

extern "C" void kernel_launch(void* const* d_in, const int* in_sizes, int n_in,
                              void* d_out, int out_size, void* d_ws, size_t ws_size,
                              hipStream_t stream) {
    const float* x    = (const float*)d_in[0];
    const float* w_h  = (const float*)d_in[1];
    const float* b_h  = (const float*)d_in[2];
    const float* w_v  = (const float*)d_in[3];
    const float* b_v  = (const float*)d_in[4];
    const float* w_d1 = (const float*)d_in[5];
    const float* b_d1 = (const float*)d_in[6];
    const float* w_d2 = (const float*)d_in[7];
    const float* b_d2 = (const float*)d_in[8];
    float* out = (float*)d_out;
    ushort* wpack = (ushort*)d_ws;   // needs 655,360 B

    repack_w<<<1280, 256, 0, stream>>>(w_h, w_v, w_d1, w_d2, wpack);
    asterisk_mfma8<<<512, 512, 0, stream>>>(x, wpack, b_h, b_v, b_d1, b_d2, out);
}